// Round 12
// baseline (161.295 us; speedup 1.0000x reference)
//
#include <hip/hip_runtime.h>
#include <hip/hip_fp16.h>

#define IN_CH 256
#define OUT_CH 8
#define LROW 264          // LDS row stride in bf16 elems: 256 + 8 pad

typedef float f32x4  __attribute__((ext_vector_type(4)));
typedef short short8v __attribute__((ext_vector_type(8)));
typedef short short4v __attribute__((ext_vector_type(4)));

__device__ __forceinline__ short f2bf(float f) {   // f32 -> bf16 (RNE)
    unsigned u = __float_as_uint(f);
    u += 0x7FFFu + ((u >> 16) & 1u);
    return (short)(u >> 16);
}

// ---------------------------------------------------------------------------
// Projection v7 EXACT (27.1 us measured via probe ladder): one wave per
// 16-row tile, ~2 tiles per wave via grid-stride (amortizes W-fragment
// build), mfma_f32_16x16x32_bf16 x8 over K=256, per-wave LDS, no barriers.
// ---------------------------------------------------------------------------
__global__ __launch_bounds__(256) void proj_kernel(
    const float* __restrict__ X,
    const float* __restrict__ W1,
    const float* __restrict__ W2,
    __half* __restrict__ P1h,        // [n][8] f16
    __half* __restrict__ P2h,
    int n, int ntiles, int nwaves)
{
    __shared__ short Xs[4][16][LROW];          // 33792 B per block

    const int wv   = threadIdx.x >> 6;
    const int lane = threadIdx.x & 63;
    const int gw   = (blockIdx.x * 256 + threadIdx.x) >> 6;

    const int o  = lane & 15;                  // output column this lane owns
    const int lk = lane >> 4;                  // k-group 0..3

    const float* wrow = (o < 8) ? (W1 + (size_t)o * IN_CH)
                                : (W2 + (size_t)(o - 8) * IN_CH);
    short8v bfr[8];
    #pragma unroll
    for (int kb = 0; kb < 8; ++kb) {
        float4 u = *(const float4*)(wrow + kb * 32 + lk * 8);
        float4 v = *(const float4*)(wrow + kb * 32 + lk * 8 + 4);
        short8v b;
        b[0] = f2bf(u.x); b[1] = f2bf(u.y); b[2] = f2bf(u.z); b[3] = f2bf(u.w);
        b[4] = f2bf(v.x); b[5] = f2bf(v.y); b[6] = f2bf(v.z); b[7] = f2bf(v.w);
        bfr[kb] = b;
    }

    for (int t = gw; t < ntiles; t += nwaves) {
        const int r0 = t * 16;

        #pragma unroll
        for (int i = 0; i < 16; ++i) {
            float4 x = make_float4(0.f, 0.f, 0.f, 0.f);
            if (r0 + i < n)
                x = *(const float4*)(X + (size_t)(r0 + i) * IN_CH + lane * 4);
            short4v s;
            s[0] = f2bf(x.x); s[1] = f2bf(x.y); s[2] = f2bf(x.z); s[3] = f2bf(x.w);
            *(short4v*)&Xs[wv][i][lane * 4] = s;
        }
        // same-wave LDS write->read: compiler inserts lgkmcnt waits

        f32x4 acc = {0.f, 0.f, 0.f, 0.f};
        #pragma unroll
        for (int kb = 0; kb < 8; ++kb) {
            short8v a = *(const short8v*)&Xs[wv][o][kb * 32 + lk * 8];
            acc = __builtin_amdgcn_mfma_f32_16x16x32_bf16(a, bfr[kb], acc, 0, 0, 0);
        }

        #pragma unroll
        for (int r = 0; r < 4; ++r) {
            const int row = r0 + lk * 4 + r;
            if (row < n) {
                __half h = __float2half(acc[r]);
                if (o < 8) P1h[(size_t)row * OUT_CH + o] = h;
                else       P2h[(size_t)row * OUT_CH + (o - 8)] = h;
            }
        }
    }
}

// ---------------------------------------------------------------------------
// Gather g6: g2 with table reads switched to agent-scope (sc0, L1-BYPASS,
// L2-cached) 8-B loads — kills the 128-B L1 line-fill amplification on the
// 12.8M random reads. Everything else byte-identical to g2 (nt idx loads,
// nt output stores).
// ---------------------------------------------------------------------------
__device__ __forceinline__ unsigned long long ld_agent(const unsigned long long* p) {
    return __hip_atomic_load(p, __ATOMIC_RELAXED, __HIP_MEMORY_SCOPE_AGENT);
}

__global__ __launch_bounds__(256) void gather_kernel(
    const int* __restrict__ e0,
    const int* __restrict__ e1,
    const unsigned long long* __restrict__ T1,   // [n*2] x 8B (4 halves each)
    const unsigned long long* __restrict__ T2,
    f32x4* __restrict__ outv,
    int E, int n)
{
    const int e = blockIdx.x * 256 + threadIdx.x;
    if (e >= E) return;
    const unsigned nmax = (unsigned)(n - 1);

    unsigned i0 = (unsigned)__builtin_nontemporal_load(e0 + e);
    unsigned i1 = (unsigned)__builtin_nontemporal_load(e1 + e);
    i0 = i0 > nmax ? nmax : i0;
    i1 = i1 > nmax ? nmax : i1;

    const unsigned long long* p1 = T1 + 2u * i0;
    const unsigned long long* p2 = T2 + 2u * i1;
    unsigned long long a0 = ld_agent(p1);
    unsigned long long a1 = ld_agent(p1 + 1);
    unsigned long long b0 = ld_agent(p2);
    unsigned long long b1 = ld_agent(p2 + 1);

    const __half2* ah0 = (const __half2*)&a0;
    const __half2* ah1 = (const __half2*)&a1;
    const __half2* bh0 = (const __half2*)&b0;
    const __half2* bh1 = (const __half2*)&b1;

    float2 s0 = __half22float2(ah0[0]);
    float2 s1 = __half22float2(ah0[1]);
    float2 s2 = __half22float2(ah1[0]);
    float2 s3 = __half22float2(ah1[1]);
    float2 t0 = __half22float2(bh0[0]);
    float2 t1 = __half22float2(bh0[1]);
    float2 t2 = __half22float2(bh1[0]);
    float2 t3 = __half22float2(bh1[1]);

    f32x4 r0 = { s0.x + t0.x, s0.y + t0.y, s1.x + t1.x, s1.y + t1.y };
    f32x4 r1 = { s2.x + t2.x, s2.y + t2.y, s3.x + t3.x, s3.y + t3.y };

    size_t oi = 2u * (size_t)e;
    __builtin_nontemporal_store(r0, outv + oi);
    __builtin_nontemporal_store(r1, outv + oi + 1);
}

extern "C" void kernel_launch(void* const* d_in, const int* in_sizes, int n_in,
                              void* d_out, int out_size, void* d_ws, size_t ws_size,
                              hipStream_t stream) {
    const float* X    = (const float*)d_in[0];
    const int*   eidx = (const int*)d_in[1];
    const float* W1   = (const float*)d_in[2];
    const float* W2   = (const float*)d_in[3];

    const int n = in_sizes[0] / IN_CH;   // 100000
    const int E = in_sizes[1] / 2;       // 6400000

    __half* P1h = (__half*)d_ws;                    // [n][8] f16 = 1.6 MB
    __half* P2h = P1h + (size_t)n * OUT_CH;         // [n][8] f16 = 1.6 MB

    const int ntiles = (n + 15) / 16;               // 6250
    const int proj_blocks = 768;                    // 3072 waves, ~2 tiles each
    const int nwaves = proj_blocks * 4;
    proj_kernel<<<proj_blocks, 256, 0, stream>>>(
        X, W1, W2, P1h, P2h, n, ntiles, nwaves);

    const int gather_blocks = (E + 255) / 256;      // 25000, 1 edge/thread
    gather_kernel<<<gather_blocks, 256, 0, stream>>>(
        eidx, eidx + E,
        (const unsigned long long*)P1h, (const unsigned long long*)P2h,
        (f32x4*)d_out, E, n);
}

// Round 13
// 136.270 us; speedup vs baseline: 1.1836x; 1.1836x over previous
//
#include <hip/hip_runtime.h>
#include <hip/hip_fp16.h>

#define IN_CH 256
#define OUT_CH 8
#define LROW 264          // LDS row stride in bf16 elems: 256 + 8 pad

typedef float f32x4  __attribute__((ext_vector_type(4)));
typedef short short8v __attribute__((ext_vector_type(8)));
typedef short short4v __attribute__((ext_vector_type(4)));

__device__ __forceinline__ short f2bf(float f) {   // f32 -> bf16 (RNE)
    unsigned u = __float_as_uint(f);
    u += 0x7FFFu + ((u >> 16) & 1u);
    return (short)(u >> 16);
}

// ---------------------------------------------------------------------------
// Projection v7 EXACT (27.1 us, probe-ladder measured): one wave per 16-row
// tile, ~2 tiles per wave via grid-stride (amortizes W-fragment build),
// mfma_f32_16x16x32_bf16 x8 over K=256, per-wave LDS slice, no barriers.
// ---------------------------------------------------------------------------
__global__ __launch_bounds__(256) void proj_kernel(
    const float* __restrict__ X,
    const float* __restrict__ W1,
    const float* __restrict__ W2,
    __half* __restrict__ P1h,        // [n][8] f16
    __half* __restrict__ P2h,
    int n, int ntiles, int nwaves)
{
    __shared__ short Xs[4][16][LROW];          // 33792 B per block

    const int wv   = threadIdx.x >> 6;
    const int lane = threadIdx.x & 63;
    const int gw   = (blockIdx.x * 256 + threadIdx.x) >> 6;

    const int o  = lane & 15;                  // output column this lane owns
    const int lk = lane >> 4;                  // k-group 0..3

    const float* wrow = (o < 8) ? (W1 + (size_t)o * IN_CH)
                                : (W2 + (size_t)(o - 8) * IN_CH);
    short8v bfr[8];
    #pragma unroll
    for (int kb = 0; kb < 8; ++kb) {
        float4 u = *(const float4*)(wrow + kb * 32 + lk * 8);
        float4 v = *(const float4*)(wrow + kb * 32 + lk * 8 + 4);
        short8v b;
        b[0] = f2bf(u.x); b[1] = f2bf(u.y); b[2] = f2bf(u.z); b[3] = f2bf(u.w);
        b[4] = f2bf(v.x); b[5] = f2bf(v.y); b[6] = f2bf(v.z); b[7] = f2bf(v.w);
        bfr[kb] = b;
    }

    for (int t = gw; t < ntiles; t += nwaves) {
        const int r0 = t * 16;

        #pragma unroll
        for (int i = 0; i < 16; ++i) {
            float4 x = make_float4(0.f, 0.f, 0.f, 0.f);
            if (r0 + i < n)
                x = *(const float4*)(X + (size_t)(r0 + i) * IN_CH + lane * 4);
            short4v s;
            s[0] = f2bf(x.x); s[1] = f2bf(x.y); s[2] = f2bf(x.z); s[3] = f2bf(x.w);
            *(short4v*)&Xs[wv][i][lane * 4] = s;
        }
        // same-wave LDS write->read: compiler inserts lgkmcnt waits

        f32x4 acc = {0.f, 0.f, 0.f, 0.f};
        #pragma unroll
        for (int kb = 0; kb < 8; ++kb) {
            short8v a = *(const short8v*)&Xs[wv][o][kb * 32 + lk * 8];
            acc = __builtin_amdgcn_mfma_f32_16x16x32_bf16(a, bfr[kb], acc, 0, 0, 0);
        }

        #pragma unroll
        for (int r = 0; r < 4; ++r) {
            const int row = r0 + lk * 4 + r;
            if (row < n) {
                __half h = __float2half(acc[r]);
                if (o < 8) P1h[(size_t)row * OUT_CH + o] = h;
                else       P2h[(size_t)row * OUT_CH + (o - 8)] = h;
            }
        }
    }
}

// ---------------------------------------------------------------------------
// Gather g7: TWO threads per edge. Even lane t=2k loads the full 16-B P1 row
// of e0[k]; odd lane loads the P2 row of e1[k]. They swap opposite 8-B
// halves via 2x shfl_xor(1), add, and lane t stores exactly the 16-B chunk
// at out+16t -> perfectly contiguous 1KB/wave nt stores.
// Random table requests per edge: 2 -> 1 (the R12-diagnosed bottleneck).
// ---------------------------------------------------------------------------
__global__ __launch_bounds__(256) void gather_kernel(
    const int* __restrict__ eidx,    // e0 = eidx, e1 = eidx + E
    const uint4* __restrict__ T1,    // [n] x 8 halves
    const uint4* __restrict__ T2,
    f32x4* __restrict__ outv,        // [2E] 16-B chunks
    int E, int n)
{
    const int t = blockIdx.x * 256 + threadIdx.x;   // chunk index, < 2E
    if (t >= 2 * E) return;

    const int e     = t >> 1;
    const int which = t & 1;                         // 0: P1/e0, 1: P2/e1
    const unsigned nmax = (unsigned)(n - 1);

    const int* ip = eidx + (which ? E : 0);
    unsigned idx = (unsigned)__builtin_nontemporal_load(ip + e);
    idx = idx > nmax ? nmax : idx;

    const uint4 row = which ? T2[idx] : T1[idx];     // ONE random 16-B read

    // keep my half, send the opposite half to my pair lane
    unsigned mine0 = which ? row.z : row.x;
    unsigned mine1 = which ? row.w : row.y;
    unsigned send0 = which ? row.x : row.z;
    unsigned send1 = which ? row.y : row.w;
    unsigned recv0 = (unsigned)__shfl_xor((int)send0, 1, 64);
    unsigned recv1 = (unsigned)__shfl_xor((int)send1, 1, 64);

    float2 f0 = __half22float2(*(const __half2*)&mine0);
    float2 f1 = __half22float2(*(const __half2*)&mine1);
    float2 g0 = __half22float2(*(const __half2*)&recv0);
    float2 g1 = __half22float2(*(const __half2*)&recv1);

    f32x4 r = { f0.x + g0.x, f0.y + g0.y, f1.x + g1.x, f1.y + g1.y };
    __builtin_nontemporal_store(r, outv + t);        // chunk t -> byte 16t
}

extern "C" void kernel_launch(void* const* d_in, const int* in_sizes, int n_in,
                              void* d_out, int out_size, void* d_ws, size_t ws_size,
                              hipStream_t stream) {
    const float* X    = (const float*)d_in[0];
    const int*   eidx = (const int*)d_in[1];
    const float* W1   = (const float*)d_in[2];
    const float* W2   = (const float*)d_in[3];

    const int n = in_sizes[0] / IN_CH;   // 100000
    const int E = in_sizes[1] / 2;       // 6400000

    __half* P1h = (__half*)d_ws;                    // [n][8] f16 = 1.6 MB
    __half* P2h = P1h + (size_t)n * OUT_CH;         // [n][8] f16 = 1.6 MB

    const int ntiles = (n + 15) / 16;               // 6250
    const int proj_blocks = 768;                    // 3072 waves, ~2 tiles each
    const int nwaves = proj_blocks * 4;
    proj_kernel<<<proj_blocks, 256, 0, stream>>>(
        X, W1, W2, P1h, P2h, n, ntiles, nwaves);

    const int gather_blocks = (2 * E + 255) / 256;  // 50000, 2 threads/edge
    gather_kernel<<<gather_blocks, 256, 0, stream>>>(
        eidx, (const uint4*)P1h, (const uint4*)P2h,
        (f32x4*)d_out, E, n);
}